// Round 6
// baseline (151.178 us; speedup 1.0000x reference)
//
#include <hip/hip_runtime.h>
#include <hip/hip_bf16.h>
#include <stdint.h>

// Round 6: DIAGNOSTIC ablation round.
//   conv_t<0>: exact R5 fused conv -> d_out (correctness).
//   conv_t<1>: staging global-loads removed (LDS zeros)   -> scrap. K-loop+epilogue cost.
//   conv_t<2>: full staging+K-loop, epilogue = 1 dword/thr -> scrap. staging+compute cost.
// All three identical otherwise: 512 thr, M=256 (2 rows), 66.5KB LDS, 2 blk/CU,
// grid 512, barrier-free 18-chunk K-loop, B preloaded 1 chunk ahead.

typedef __bf16 bf16t;
typedef __bf16 bf16x8 __attribute__((ext_vector_type(8)));
typedef float  f32x4  __attribute__((ext_vector_type(4)));

#define CIN   64
#define COUT  96
#define HH    128
#define WW    128
#define KTOT  576
#define NCH   18
#define XROW  (130 * 32)
#define XTOT  (4 * XROW)          // 66560 B

__device__ __forceinline__ int swz8(int px) { return ((px >> 2) & 7) ^ ((px & 3) << 1); }

__device__ __forceinline__ uint32_t pack2(float lo, float hi) {
    uint16_t a = __builtin_bit_cast(uint16_t, (__bf16)lo);
    uint16_t b = __builtin_bit_cast(uint16_t, (__bf16)hi);
    return ((uint32_t)b << 16) | (uint32_t)a;
}

__global__ __launch_bounds__(256) void prep_w_kernel(
    const float* __restrict__ W, bf16t* __restrict__ Wp)
{
    int idx = blockIdx.x * 256 + threadIdx.x;
    if (idx >= NCH * COUT * 32) return;
    int ch  = idx / (COUT * 32);
    int rem = idx - ch * (COUT * 32);
    int n = rem >> 5, cc = rem & 31;
    int r = ch >> 1, half = ch & 1;
    Wp[idx] = (bf16t)W[n * KTOT + (half * 32 + cc) * 9 + r];
}

template<int MODE>
__global__ __launch_bounds__(512, 4) void conv_t(
    const float* __restrict__ x, const bf16t* __restrict__ Wp,
    const float* __restrict__ bias, float* __restrict__ out)
{
    __shared__ __align__(16) uint32_t Xs[XTOT];

    const int tid  = threadIdx.x;
    const int lane = tid & 63;
    const int wave = tid >> 6;
    const int lrow = lane & 15;
    const int quad = lane >> 4;
    const int wn   = wave & 1;
    const int wm   = wave >> 1;

    const int bb  = blockIdx.x & 7;
    const int orp = blockIdx.x >> 3;

    const bf16t* wp_n = Wp + (size_t)(wn * 48 + lrow) * 32 + quad * 8;

    bf16x8 bcur[3], bnxt[3];
    #pragma unroll
    for (int nt = 0; nt < 3; ++nt)
        bcur[nt] = *(const bf16x8*)(wp_n + nt * 512);

    uint4* X4 = (uint4*)Xs;
    #pragma unroll
    for (int i = 0; i < 9; ++i) {
        int idx = tid + 512 * i;
        if (idx < XTOT / 4) X4[idx] = (uint4){0u, 0u, 0u, 0u};
    }
    __syncthreads();

    if constexpr (MODE != 1) {   // MODE 1: skip staging (ablate global x reads)
        const float* xb = x + (size_t)bb * CIN * HH * WW;
        #pragma unroll
        for (int it = 0; it < 8; ++it) {
            int g  = tid + 512 * it;
            int j0 = (g & 31) * 4;
            int cp = (g >> 5) & 31;
            int rh = g >> 10;
            int ii = orp * 2 - 1 + rh;
            if ((unsigned)ii < (unsigned)HH) {
                const float* s0 = xb + ((size_t)(2 * cp) * HH + ii) * WW + j0;
                float4 v0 = *(const float4*)s0;
                float4 v1 = *(const float4*)(s0 + HH * WW);
                float e0[4] = {v0.x, v0.y, v0.z, v0.w};
                float e1[4] = {v1.x, v1.y, v1.z, v1.w};
                #pragma unroll
                for (int u = 0; u < 4; ++u) {
                    int px  = 1 + j0 + u;
                    int cdw = (cp & 3) | ((((cp >> 2) ^ swz8(px)) & 7) << 2);
                    Xs[rh * XROW + px * 32 + cdw] = pack2(e0[u], e1[u]);
                }
            }
        }
    }
    __syncthreads();

    f32x4 acc[4][3];
    #pragma unroll
    for (int a = 0; a < 4; ++a)
        #pragma unroll
        for (int nt = 0; nt < 3; ++nt)
            acc[a][nt] = (f32x4){0.f, 0.f, 0.f, 0.f};

    #pragma unroll
    for (int ch = 0; ch < NCH; ++ch) {
        if (ch < NCH - 1) {
            #pragma unroll
            for (int nt = 0; nt < 3; ++nt)
                bnxt[nt] = *(const bf16x8*)(wp_n + (size_t)(ch + 1) * 3072 + nt * 512);
        }
        const int ki = ch / 6, kj = (ch % 6) >> 1, half = ch & 1;
        bf16x8 afr[4];
        #pragma unroll
        for (int a = 0; a < 4; ++a) {
            int mb   = wm * 64 + a * 16;
            int slab = (mb >> 7) + ki;
            int p    = (mb & 127) + lrow + kj;
            int blk  = (half * 4 + quad) ^ swz8(p);
            afr[a] = *(const bf16x8*)&Xs[slab * XROW + p * 32 + blk * 4];
        }
        #pragma unroll
        for (int a = 0; a < 4; ++a)
            #pragma unroll
            for (int nt = 0; nt < 3; ++nt)
                acc[a][nt] = __builtin_amdgcn_mfma_f32_16x16x32_bf16(
                    afr[a], bcur[nt], acc[a][nt], 0, 0, 0);
        #pragma unroll
        for (int nt = 0; nt < 3; ++nt) bcur[nt] = bnxt[nt];
    }

    if constexpr (MODE == 2) {   // ablate epilogue: 1 dword per thread sink
        float s = 0.f;
        #pragma unroll
        for (int a = 0; a < 4; ++a)
            #pragma unroll
            for (int nt = 0; nt < 3; ++nt)
                #pragma unroll
                for (int rg = 0; rg < 4; ++rg)
                    s += acc[a][nt][rg];
        out[(size_t)blockIdx.x * 512 + tid] = s;
        return;
    }

    float bv[3];
    #pragma unroll
    for (int nt = 0; nt < 3; ++nt) bv[nt] = bias[wn * 48 + nt * 16 + lrow];

    float* outp = out + ((size_t)bb * 16384 + (size_t)orp * 256) * COUT + wn * 48;
    #pragma unroll
    for (int a = 0; a < 4; ++a) {
        #pragma unroll
        for (int rg = 0; rg < 4; ++rg) {
            int mm = wm * 64 + a * 16 + quad * 4 + rg;
            float* rowp = outp + (size_t)mm * COUT;
            #pragma unroll
            for (int nt = 0; nt < 3; ++nt)
                rowp[nt * 16 + lrow] = acc[a][nt][rg] + bv[nt];
        }
    }
}

extern "C" void kernel_launch(void* const* d_in, const int* in_sizes, int n_in,
                              void* d_out, int out_size, void* d_ws, size_t ws_size,
                              hipStream_t stream) {
    const float* x    = (const float*)d_in[0];   // (8,64,128,128)
    const float* W    = (const float*)d_in[1];   // (96,576)
    const float* bias = (const float*)d_in[2];   // (96,)
    float* out = (float*)d_out;                  // (8,16384,96)

    bf16t* Wp     = (bf16t*)d_ws;                             // 110592 B
    float* scrap1 = (float*)((char*)d_ws + (size_t)(2  << 20));  // 50.3 MB region
    float* scrap2 = (float*)((char*)d_ws + (size_t)(96 << 20));  // 1 MB region

    hipLaunchKernelGGL(prep_w_kernel, dim3((NCH * COUT * 32 + 255) / 256), dim3(256), 0, stream,
                       W, Wp);
    // A-leg: exact R5 conv, correctness output.
    hipLaunchKernelGGL((conv_t<0>), dim3(512), dim3(512), 0, stream, x, Wp, bias, out);
    // Probe 1: no staging (K-loop + epilogue cost).
    hipLaunchKernelGGL((conv_t<1>), dim3(512), dim3(512), 0, stream, x, Wp, bias, scrap1);
    // Probe 2: no epilogue (staging + K-loop cost).
    hipLaunchKernelGGL((conv_t<2>), dim3(512), dim3(512), 0, stream, x, Wp, bias, scrap2);
}

// Round 7
// 111.689 us; speedup vs baseline: 1.3536x; 1.3536x over previous
//
#include <hip/hip_runtime.h>
#include <hip/hip_bf16.h>
#include <stdint.h>

// SoftSplit = unfold(3x3,pad1)+linear == 3x3 same-conv Cin=64->Cout=96,
// out (8,16384,96) fp32. Round 7: memory-phase attack.
//  - M=128/block (one output row), 256 thr, 3 LDS slabs (49.9 KB) -> 3 blk/CU,
//    grid 1024 -> 1.33x oversubscription (phase desync/overlap).
//  - Staging: software-pipelined register batches (8 float4 in flight while
//    previous slab packs to LDS) -> MLP ~8/wave instead of load->write chains.
//  - Halo: only 2 columns zeroed; OOB rows via block-uniform zero branch.
//  - K-loop: R5's proven barrier-free 18-chunk loop, B 1 chunk ahead in regs.

typedef __bf16 bf16t;
typedef __bf16 bf16x8 __attribute__((ext_vector_type(8)));
typedef float  f32x4  __attribute__((ext_vector_type(4)));

#define CIN   64
#define COUT  96
#define HH    128
#define WW    128
#define KTOT  576
#define NCH   18
#define XROW  (130 * 32)          // dwords per slab (130 px * 32 dw)

__device__ __forceinline__ int swz8(int px) { return ((px >> 2) & 7) ^ ((px & 3) << 1); }

__device__ __forceinline__ uint32_t pack2(float lo, float hi) {
    uint16_t a = __builtin_bit_cast(uint16_t, (__bf16)lo);
    uint16_t b = __builtin_bit_cast(uint16_t, (__bf16)hi);
    return ((uint32_t)b << 16) | (uint32_t)a;
}

__global__ __launch_bounds__(256) void prep_w_kernel(
    const float* __restrict__ W, bf16t* __restrict__ Wp)
{
    int idx = blockIdx.x * 256 + threadIdx.x;
    if (idx >= NCH * COUT * 32) return;
    int ch  = idx / (COUT * 32);
    int rem = idx - ch * (COUT * 32);
    int n = rem >> 5, cc = rem & 31;
    int r = ch >> 1, half = ch & 1;
    Wp[idx] = (bf16t)W[n * KTOT + (half * 32 + cc) * 9 + r];
}

__global__ __launch_bounds__(256, 3) void conv_kernel(
    const float* __restrict__ x, const bf16t* __restrict__ Wp,
    const float* __restrict__ bias, float* __restrict__ out)
{
    __shared__ __align__(16) uint32_t Xs[3 * XROW];   // 49920 B -> 3 blocks/CU

    const int tid  = threadIdx.x;
    const int lane = tid & 63;
    const int wave = tid >> 6;
    const int lrow = lane & 15;
    const int quad = lane >> 4;
    const int wn   = wave & 1;       // n-group: cols wn*48..+47 (3 n-tiles)
    const int wm   = wave >> 1;      // m-group: pixels wm*64..+63 (4 m-tiles)

    const int bb = blockIdx.x & 7;   // batch -> XCD-local
    const int oi = blockIdx.x >> 3;  // output row 0..127

    const bf16t* wp_n = Wp + (size_t)(wn * 48 + lrow) * 32 + quad * 8;

    // chunk-0 B loads first (latency hides behind staging)
    bf16x8 bcur[3], bnxt[3];
    #pragma unroll
    for (int nt = 0; nt < 3; ++nt)
        bcur[nt] = *(const bf16x8*)(wp_n + nt * 512);

    // zero only halo columns px=0,129 (3 slabs x 2 cols x 32 dw = 192 dw)
    if (tid < 192) {
        int s = tid >> 6, c129 = (tid >> 5) & 1, dw = tid & 31;
        Xs[s * XROW + (c129 ? 129 : 0) * 32 + dw] = 0u;
    }

    // ---- staging: 3 slabs, register-batched + cross-slab pipelined ----
    const float* xb = x + (size_t)bb * CIN * HH * WW;
    const int j0  = (tid & 31) * 4;   // px-quad
    const int cp0 = tid >> 5;         // channel-pair base; pair = q*8 + cp0
    float4 vb[2][8];

    {   // issue slab-0 loads
        int ii = oi - 1;
        if (ii >= 0) {
            #pragma unroll
            for (int q = 0; q < 4; ++q) {
                const float* s0 = xb + ((size_t)(2 * (q * 8 + cp0)) * HH + ii) * WW + j0;
                vb[0][2 * q]     = *(const float4*)s0;
                vb[0][2 * q + 1] = *(const float4*)(s0 + HH * WW);
            }
        } else {
            #pragma unroll
            for (int i = 0; i < 8; ++i) vb[0][i] = (float4){0.f, 0.f, 0.f, 0.f};
        }
    }
    #pragma unroll
    for (int s = 0; s < 3; ++s) {
        if (s < 2) {   // issue slab s+1 loads into the other buffer
            int ii = oi + s;
            if (ii < HH) {
                #pragma unroll
                for (int q = 0; q < 4; ++q) {
                    const float* s0 = xb + ((size_t)(2 * (q * 8 + cp0)) * HH + ii) * WW + j0;
                    vb[(s + 1) & 1][2 * q]     = *(const float4*)s0;
                    vb[(s + 1) & 1][2 * q + 1] = *(const float4*)(s0 + HH * WW);
                }
            } else {
                #pragma unroll
                for (int i = 0; i < 8; ++i) vb[(s + 1) & 1][i] = (float4){0.f, 0.f, 0.f, 0.f};
            }
        }
        #pragma unroll
        for (int q = 0; q < 4; ++q) {   // pack + LDS-write slab s
            int cpp = q * 8 + cp0;      // channel pair 0..31
            float e0[4] = {vb[s & 1][2 * q].x, vb[s & 1][2 * q].y,
                           vb[s & 1][2 * q].z, vb[s & 1][2 * q].w};
            float e1[4] = {vb[s & 1][2 * q + 1].x, vb[s & 1][2 * q + 1].y,
                           vb[s & 1][2 * q + 1].z, vb[s & 1][2 * q + 1].w};
            #pragma unroll
            for (int u = 0; u < 4; ++u) {
                int px  = 1 + j0 + u;
                int cdw = (cpp & 3) | ((((cpp >> 2) ^ swz8(px)) & 7) << 2);
                Xs[s * XROW + px * 32 + cdw] = pack2(e0[u], e1[u]);
            }
        }
    }
    __syncthreads();

    // ---- barrier-free K-loop: 18 chunks, B one chunk ahead ----
    f32x4 acc[4][3];
    #pragma unroll
    for (int a = 0; a < 4; ++a)
        #pragma unroll
        for (int nt = 0; nt < 3; ++nt)
            acc[a][nt] = (f32x4){0.f, 0.f, 0.f, 0.f};

    #pragma unroll
    for (int ch = 0; ch < NCH; ++ch) {
        if (ch < NCH - 1) {
            #pragma unroll
            for (int nt = 0; nt < 3; ++nt)
                bnxt[nt] = *(const bf16x8*)(wp_n + (size_t)(ch + 1) * 3072 + nt * 512);
        }
        const int ki = ch / 6, kj = (ch % 6) >> 1, half = ch & 1;
        bf16x8 afr[4];
        #pragma unroll
        for (int a = 0; a < 4; ++a) {
            int p   = wm * 64 + a * 16 + lrow + kj;
            int blk = (half * 4 + quad) ^ swz8(p);
            afr[a] = *(const bf16x8*)&Xs[ki * XROW + p * 32 + blk * 4];
        }
        #pragma unroll
        for (int a = 0; a < 4; ++a)
            #pragma unroll
            for (int nt = 0; nt < 3; ++nt)
                acc[a][nt] = __builtin_amdgcn_mfma_f32_16x16x32_bf16(
                    afr[a], bcur[nt], acc[a][nt], 0, 0, 0);
        #pragma unroll
        for (int nt = 0; nt < 3; ++nt) bcur[nt] = bnxt[nt];
    }

    // ---- epilogue: D col=lane&15 (c2), row=quad*4+reg (pixel) ----
    float bv[3];
    #pragma unroll
    for (int nt = 0; nt < 3; ++nt) bv[nt] = bias[wn * 48 + nt * 16 + lrow];

    float* outp = out + ((size_t)bb * 16384 + (size_t)oi * 128) * COUT + wn * 48;
    #pragma unroll
    for (int a = 0; a < 4; ++a) {
        #pragma unroll
        for (int rg = 0; rg < 4; ++rg) {
            int mm = wm * 64 + a * 16 + quad * 4 + rg;
            float* rowp = outp + (size_t)mm * COUT;
            #pragma unroll
            for (int nt = 0; nt < 3; ++nt)
                rowp[nt * 16 + lrow] = acc[a][nt][rg] + bv[nt];
        }
    }
}

extern "C" void kernel_launch(void* const* d_in, const int* in_sizes, int n_in,
                              void* d_out, int out_size, void* d_ws, size_t ws_size,
                              hipStream_t stream) {
    const float* x    = (const float*)d_in[0];   // (8,64,128,128)
    const float* W    = (const float*)d_in[1];   // (96,576)
    const float* bias = (const float*)d_in[2];   // (96,)
    float* out = (float*)d_out;                  // (8,16384,96)
    bf16t* Wp  = (bf16t*)d_ws;                   // 110592 B scratch

    hipLaunchKernelGGL(prep_w_kernel, dim3((NCH * COUT * 32 + 255) / 256), dim3(256), 0, stream,
                       W, Wp);
    hipLaunchKernelGGL(conv_kernel, dim3(1024), dim3(256), 0, stream,
                       x, Wp, bias, out);
}

// Round 8
// 109.320 us; speedup vs baseline: 1.3829x; 1.0217x over previous
//
#include <hip/hip_runtime.h>
#include <hip/hip_bf16.h>
#include <stdint.h>

// SoftSplit = unfold(3x3,pad1)+linear == 3x3 same-conv Cin=64->Cout=96,
// out (8,16384,96) fp32. Round 8: R5 fused kernel + VECTORIZED EPILOGUE.
//  Theory: scalar dword stores run ~3 TB/s (m18 precedent); 53 MB epilogue
//  was ~16 us of the ~37 us kernel. Transpose C through LDS (free after
//  K-loop) and store float4 (6 per thread vs 48 scalar).
//  Everything else identical to R5: 512 thr, M=256 (2 rows), 66.5 KB LDS,
//  2 blk/CU, grid 512, barrier-free 18-chunk K-loop, B 1 chunk ahead.

typedef __bf16 bf16t;
typedef __bf16 bf16x8 __attribute__((ext_vector_type(8)));
typedef float  f32x4  __attribute__((ext_vector_type(4)));

#define CIN   64
#define COUT  96
#define HH    128
#define WW    128
#define KTOT  576
#define NCH   18
#define XROW  (130 * 32)          // dwords per staged row slab
#define XTOT  (4 * XROW)          // 16640 dw = 66560 B
#define OS    100                 // out-transpose LDS row stride (dw), 16B-aligned, 2-way banks

__device__ __forceinline__ int swz8(int px) { return ((px >> 2) & 7) ^ ((px & 3) << 1); }

__device__ __forceinline__ uint32_t pack2(float lo, float hi) {
    uint16_t a = __builtin_bit_cast(uint16_t, (__bf16)lo);
    uint16_t b = __builtin_bit_cast(uint16_t, (__bf16)hi);
    return ((uint32_t)b << 16) | (uint32_t)a;
}

__global__ __launch_bounds__(256) void prep_w_kernel(
    const float* __restrict__ W, bf16t* __restrict__ Wp)
{
    int idx = blockIdx.x * 256 + threadIdx.x;
    if (idx >= NCH * COUT * 32) return;
    int ch  = idx / (COUT * 32);
    int rem = idx - ch * (COUT * 32);
    int n = rem >> 5, cc = rem & 31;
    int r = ch >> 1, half = ch & 1;
    Wp[idx] = (bf16t)W[n * KTOT + (half * 32 + cc) * 9 + r];
}

__global__ __launch_bounds__(512, 4) void conv_kernel(
    const float* __restrict__ x, const bf16t* __restrict__ Wp,
    const float* __restrict__ bias, float* __restrict__ out)
{
    __shared__ __align__(16) uint32_t Xs[XTOT];

    const int tid  = threadIdx.x;
    const int lane = tid & 63;
    const int wave = tid >> 6;
    const int lrow = lane & 15;
    const int quad = lane >> 4;
    const int wn   = wave & 1;       // n-group: cols wn*48..+47 (3 n-tiles)
    const int wm   = wave >> 1;      // m-group: pixels wm*64..+63 (4 m-tiles)

    const int bb  = blockIdx.x & 7;  // batch -> XCD-local
    const int orp = blockIdx.x >> 3; // output row-pair 0..63

    const bf16t* wp_n = Wp + (size_t)(wn * 48 + lrow) * 32 + quad * 8;

    // ---- chunk-0 B loads first (latency hides behind staging) ----
    bf16x8 bcur[3], bnxt[3];
    #pragma unroll
    for (int nt = 0; nt < 3; ++nt)
        bcur[nt] = *(const bf16x8*)(wp_n + nt * 512);

    // ---- zero LDS (halo rows/cols must read 0) ----
    uint4* X4 = (uint4*)Xs;
    #pragma unroll
    for (int i = 0; i < 9; ++i) {
        int idx = tid + 512 * i;
        if (idx < XTOT / 4) X4[idx] = (uint4){0u, 0u, 0u, 0u};
    }
    __syncthreads();

    // ---- stage 4 input rows: NCHW fp32 -> swizzled NHWC bf16 ----
    const float* xb = x + (size_t)bb * CIN * HH * WW;
    #pragma unroll
    for (int it = 0; it < 8; ++it) {
        int g  = tid + 512 * it;          // 0..4095 = 4 rows * 32 cp * 32 jg
        int j0 = (g & 31) * 4;
        int cp = (g >> 5) & 31;
        int rh = g >> 10;                 // 0..3
        int ii = orp * 2 - 1 + rh;
        if ((unsigned)ii < (unsigned)HH) {
            const float* s0 = xb + ((size_t)(2 * cp) * HH + ii) * WW + j0;
            float4 v0 = *(const float4*)s0;
            float4 v1 = *(const float4*)(s0 + HH * WW);
            float e0[4] = {v0.x, v0.y, v0.z, v0.w};
            float e1[4] = {v1.x, v1.y, v1.z, v1.w};
            #pragma unroll
            for (int u = 0; u < 4; ++u) {
                int px  = 1 + j0 + u;
                int cdw = (cp & 3) | ((((cp >> 2) ^ swz8(px)) & 7) << 2);
                Xs[rh * XROW + px * 32 + cdw] = pack2(e0[u], e1[u]);
            }
        }
    }
    __syncthreads();

    // ---- barrier-free K-loop: 18 chunks, B one chunk ahead ----
    f32x4 acc[4][3];
    #pragma unroll
    for (int a = 0; a < 4; ++a)
        #pragma unroll
        for (int nt = 0; nt < 3; ++nt)
            acc[a][nt] = (f32x4){0.f, 0.f, 0.f, 0.f};

    #pragma unroll
    for (int ch = 0; ch < NCH; ++ch) {
        if (ch < NCH - 1) {
            #pragma unroll
            for (int nt = 0; nt < 3; ++nt)
                bnxt[nt] = *(const bf16x8*)(wp_n + (size_t)(ch + 1) * 3072 + nt * 512);
        }
        const int ki = ch / 6, kj = (ch % 6) >> 1, half = ch & 1;
        bf16x8 afr[4];
        #pragma unroll
        for (int a = 0; a < 4; ++a) {
            int mb   = wm * 64 + a * 16;
            int slab = (mb >> 7) + ki;
            int p    = (mb & 127) + lrow + kj;
            int blk  = (half * 4 + quad) ^ swz8(p);
            afr[a] = *(const bf16x8*)&Xs[slab * XROW + p * 32 + blk * 4];
        }
        #pragma unroll
        for (int a = 0; a < 4; ++a)
            #pragma unroll
            for (int nt = 0; nt < 3; ++nt)
                acc[a][nt] = __builtin_amdgcn_mfma_f32_16x16x32_bf16(
                    afr[a], bcur[nt], acc[a][nt], 0, 0, 0);
        #pragma unroll
        for (int nt = 0; nt < 3; ++nt) bcur[nt] = bnxt[nt];
    }

    // ---- epilogue: LDS transpose -> float4 stores (two 128-px halves) ----
    float bv[3];
    #pragma unroll
    for (int nt = 0; nt < 3; ++nt) bv[nt] = bias[wn * 48 + nt * 16 + lrow];

    float* Of = (float*)Xs;    // 128 * OS * 4B = 51200 B <= 66560 B
    float* outp = out + ((size_t)bb * 16384 + (size_t)orp * 256) * COUT;

    #pragma unroll
    for (int h = 0; h < 2; ++h) {
        __syncthreads();   // h=0: K-loop LDS reads done; h=1: prev round read done
        if ((wm >> 1) == h) {
            #pragma unroll
            for (int a = 0; a < 4; ++a) {
                int pxl = (wm & 1) * 64 + a * 16 + quad * 4;   // 0..124 in half
                #pragma unroll
                for (int rg = 0; rg < 4; ++rg)
                    #pragma unroll
                    for (int nt = 0; nt < 3; ++nt)
                        Of[(pxl + rg) * OS + wn * 48 + nt * 16 + lrow] =
                            acc[a][nt][rg] + bv[nt];
            }
        }
        __syncthreads();
        // 128 px * 24 float4 = 3072; 512 thr -> 6 each; coalesced stores
        #pragma unroll
        for (int r = 0; r < 6; ++r) {
            int idx = r * 512 + tid;
            int px  = idx / 24, c4 = idx - px * 24;
            float4 v = *(const float4*)&Of[px * OS + c4 * 4];
            *(float4*)(outp + (size_t)(h * 128 + px) * COUT + c4 * 4) = v;
        }
    }
}

extern "C" void kernel_launch(void* const* d_in, const int* in_sizes, int n_in,
                              void* d_out, int out_size, void* d_ws, size_t ws_size,
                              hipStream_t stream) {
    const float* x    = (const float*)d_in[0];   // (8,64,128,128)
    const float* W    = (const float*)d_in[1];   // (96,576)
    const float* bias = (const float*)d_in[2];   // (96,)
    float* out = (float*)d_out;                  // (8,16384,96)
    bf16t* Wp  = (bf16t*)d_ws;                   // 110592 B scratch

    hipLaunchKernelGGL(prep_w_kernel, dim3((NCH * COUT * 32 + 255) / 256), dim3(256), 0, stream,
                       W, Wp);
    hipLaunchKernelGGL(conv_kernel, dim3(512), dim3(512), 0, stream,
                       x, Wp, bias, out);
}